// Round 2
// baseline (743.090 us; speedup 1.0000x reference)
//
#include <hip/hip_runtime.h>
#include <hip/hip_fp16.h>

#define NB 512   // batch
#define NT 512   // time steps
#define NL 126   // labels
#define NS 128   // states (start=126, end=127)
#define SIGMA 0.0625f   // lagged-normalizer target scale (1/16)

typedef _Float16 h2 __attribute__((ext_vector_type(2)));

static __device__ __forceinline__ int pk_from(float a, float b) {
  return __builtin_bit_cast(int, __builtin_amdgcn_cvt_pkrtz(a, b));
}
// round-to-nearest-even f32->f16 pack (matches the validated u-write rounding)
static __device__ __forceinline__ int pk_rne(float a, float b) {
  h2 p; p.x = (_Float16)a; p.y = (_Float16)b;
  return __builtin_bit_cast(int, p);
}
// guaranteed-packed fp16 ops on int-carried pairs
static __device__ __forceinline__ int pkmul(int a, int b) {
  int d; asm("v_pk_mul_f16 %0, %1, %2" : "=v"(d) : "v"(a), "v"(b)); return d;
}
static __device__ __forceinline__ int pkmax(int a, int b) {
  int d; asm("v_pk_max_f16 %0, %1, %2" : "=v"(d) : "v"(a), "v"(b)); return d;
}
static __device__ __forceinline__ int pkadd(int a, int b) {
  int d; asm("v_pk_add_f16 %0, %1, %2" : "=v"(d) : "v"(a), "v"(b)); return d;
}

// wave64 add-reduce to lane 63, ONE instruction per stage (v_add_f32_dpp).
// Same numeric tree as the validated R0/R1 macro.
#define WAVE_ADD(x) do { \
  asm("v_add_f32_dpp %0, %0, %0 row_shr:1  row_mask:0xf bank_mask:0xf bound_ctrl:0" : "+v"(x)); \
  asm("v_add_f32_dpp %0, %0, %0 row_shr:2  row_mask:0xf bank_mask:0xf bound_ctrl:0" : "+v"(x)); \
  asm("v_add_f32_dpp %0, %0, %0 row_shr:4  row_mask:0xf bank_mask:0xf bound_ctrl:0" : "+v"(x)); \
  asm("v_add_f32_dpp %0, %0, %0 row_shr:8  row_mask:0xf bank_mask:0xf bound_ctrl:0" : "+v"(x)); \
  asm("v_add_f32_dpp %0, %0, %0 row_bcast:15 row_mask:0xa bank_mask:0xf bound_ctrl:0" : "+v"(x)); \
  asm("v_add_f32_dpp %0, %0, %0 row_bcast:31 row_mask:0xc bank_mask:0xf bound_ctrl:0" : "+v"(x)); \
} while (0)

// ONE WAVE PER BATCH ELEMENT — zero barriers. Lane l owns columns (2l, 2l+1),
// all 128 rows. The u-vector (128 fp16 = 64 packed ints) lives in a single
// 256B LDS buffer: each lane writes its packed pair, then ALL lanes broadcast-
// read the whole vector (same-address b128 reads = conflict-free broadcast).
// Per-wave DS queue is in-order, so write->read needs no barrier, no ping-pong.
// The 16 ds_read_b128 for step t+1 are issued right after the ds_write and
// their latency hides under the WAVE_ADD/log tail + next step's exp work.
// Cross-lane scalars (S, Z) via DPP reduce + __shfl broadcast; normalizer Z
// lagged one step exactly as the validated R5 math.
__global__ __launch_bounds__(64, 1) void crf_kernel(
    const float* __restrict__ emissions,   // [NB, NT, NL]
    const int*   __restrict__ labels,      // [NB, NT]
    const float* __restrict__ trans,       // [NS, NS]
    float*       __restrict__ out)
{
  const int b   = blockIdx.x;
  const int ln  = threadIdx.x;            // 0..63, single wave
  const int c0  = 2 * ln;                 // columns owned by this lane
  const int c1  = c0 + 1;
  const bool has = (ln < 63);             // lanes whose columns are real labels

  __shared__ __align__(16) int u_lds[64]; // 128 fp16, packed by column pair

  const float* em  = emissions + (size_t)b * NT * NL;
  const int*   lab = labels + (size_t)b * NT;

  // ---- per-column max tau (exact fp32) ----
  float tau0 = -3.0e38f, tau1 = -3.0e38f;
  for (int rr = 0; rr < NS; rr++) {
    float2 tr = *(const float2*)&trans[rr * NS + c0];
    tau0 = fmaxf(tau0, tr.x);
    tau1 = fmaxf(tau1, tr.y);
  }

  // ---- tab[c][k] = rows (2k, 2k+1) of exp(T[.][c]-tau_c), packed fp16 ----
  int tabA[64], tabB[64];
  #pragma unroll
  for (int k = 0; k < 64; k++) {
    float2 r0 = *(const float2*)&trans[(2 * k) * NS + c0];
    float2 r1 = *(const float2*)&trans[(2 * k + 1) * NS + c0];
    tabA[k] = pk_from(__expf(r0.x - tau0), __expf(r1.x - tau0));
    tabB[k] = pk_from(__expf(r0.y - tau1), __expf(r1.y - tau1));
  }

  // ---- gold path partial (8 timesteps per lane) ----
  float realp = 0.f;
  #pragma unroll
  for (int q = 0; q < 8; q++) {
    int t  = ln + q * 64;
    int la = lab[t];
    int na = (t + 1 < NT) ? lab[t + 1] : (NL + 1);
    realp += em[t * NL + la] + trans[la * NS + na];
  }
  if (ln == 0) realp += trans[NL * NS + lab[0]];

  // ---- init: v = delta at start state (col 126 = 1) ----
  u_lds[ln] = (ln == 63) ? pk_rne(1.f, 0.f) : 0;

  // ---- rolling 2-deep emission prefetch (float2 per lane, coalesced) ----
  float2 emc, emn;
  if (has) {
    emc = *(const float2*)&em[c0];
    emn = *(const float2*)&em[NL + c0];
  } else {
    emc.x = emc.y = 0.f; emn.x = emn.y = 0.f;
  }

  // ---- preload u for step 0 (broadcast reads, in-order after the write) ----
  int4 uu[16];
  {
    const int4* up = (const int4*)u_lds;
    #pragma unroll
    for (int j = 0; j < 16; j++) uu[j] = up[j];
  }

  float Cc = 0.f, Q = 0.f, r = SIGMA;   // r: Z lagged one step (Z_init = 1)

  #pragma unroll 1
  for (int t = 0; t <= NT; t++) {
    // ---- g = exp(obs + tau) from prefetched emission ----
    float obs0, obs1;
    if (t < NT) {
      obs0 = has ? emc.x : -1000.f;     // col 126 (start) gets -1000
      obs1 = has ? emc.y : -1000.f;     // col 127 (end) gets -1000
    } else {
      obs0 = -1000.f;
      obs1 = (ln == 63) ? 0.f : -1000.f; // final step: end state observed
    }
    float g0 = __expf(obs0 + tau0);
    float g1 = __expf(obs1 + tau1);

    // issue t+2 emission prefetch early (global latency hidden under tree)
    float2 ef;
    if (t + 2 < NT && has) ef = *(const float2*)&em[(t + 2) * NL + c0];
    else { ef.x = 0.f; ef.y = 0.f; }
    emc = emn; emn = ef;

    // ---- critical path: 128 rows x 2 columns, packed fp16, 16 acc chains ----
    int h0a=0,h0b=0,h0c=0,h0d=0, s0a=0,s0b=0,s0c=0,s0d=0;
    int h1a=0,h1b=0,h1c=0,h1d=0, s1a=0,s1b=0,s1c=0,s1d=0;
    #pragma unroll
    for (int j = 0; j < 16; j++) {
      int m;
      m = pkmul(uu[j].x, tabA[4*j+0]); h0a = pkmax(h0a,m); s0a = pkadd(s0a,m);
      m = pkmul(uu[j].y, tabA[4*j+1]); h0b = pkmax(h0b,m); s0b = pkadd(s0b,m);
      m = pkmul(uu[j].z, tabA[4*j+2]); h0c = pkmax(h0c,m); s0c = pkadd(s0c,m);
      m = pkmul(uu[j].w, tabA[4*j+3]); h0d = pkmax(h0d,m); s0d = pkadd(s0d,m);
      m = pkmul(uu[j].x, tabB[4*j+0]); h1a = pkmax(h1a,m); s1a = pkadd(s1a,m);
      m = pkmul(uu[j].y, tabB[4*j+1]); h1b = pkmax(h1b,m); s1b = pkadd(s1b,m);
      m = pkmul(uu[j].z, tabB[4*j+2]); h1c = pkmax(h1c,m); s1c = pkadd(s1c,m);
      m = pkmul(uu[j].w, tabB[4*j+3]); h1d = pkmax(h1d,m); s1d = pkadd(s1d,m);
    }
    int hv0 = pkmax(pkmax(h0a,h0b), pkmax(h0c,h0d));
    int sv0 = pkadd(pkadd(s0a,s0b), pkadd(s0c,s0d));
    int hv1 = pkmax(pkmax(h1a,h1b), pkmax(h1c,h1d));
    int sv1 = pkadd(pkadd(s1a,s1b), pkadd(s1c,s1d));
    h2 hh0 = __builtin_bit_cast(h2, hv0);
    h2 ss0 = __builtin_bit_cast(h2, sv0);
    h2 hh1 = __builtin_bit_cast(h2, hv1);
    h2 ss1 = __builtin_bit_cast(h2, sv1);
    float h0 = fmaxf(fmaxf((float)hh0.x, (float)hh0.y), 1e-30f);
    float s0 = (float)ss0.x + (float)ss0.y;
    float h1 = fmaxf(fmaxf((float)hh1.x, (float)hh1.y), 1e-30f);
    float s1 = (float)ss1.x + (float)ss1.y;

    float w0 = h0 * g0, v0 = w0 * r;
    float w1 = h1 * g1, v1 = w1 * r;

    // ---- write new u, then IMMEDIATELY issue next step's broadcast reads
    //      (per-wave DS queue is in-order; latency hides under the tail) ----
    u_lds[ln] = pk_rne(v0, v1);
    {
      const int4* up = (const int4*)u_lds;
      #pragma unroll
      for (int j = 0; j < 16; j++) uu[j] = up[j];
    }

    // ---- off-path tail: scalars for this step (used next step via lag) ----
    float contrib = s0 * __builtin_amdgcn_rcpf(h0)
                  + s1 * __builtin_amdgcn_rcpf(h1);
    float zz = v0 + v1;
    WAVE_ADD(contrib);
    WAVE_ADD(zz);
    float S = __shfl(contrib, 63);
    float Z = __shfl(zz, 63);
    Cc += __logf(S);
    Q  += __logf(Z);
    r = SIGMA * __builtin_amdgcn_rcpf(Z);
  }

  // total = Cc + Q + (NT+1)*log(1/SIGMA); one atomic per wave
  WAVE_ADD(realp);
  if (ln == 63) {
    const float CONST = 513.f * 2.772588722f;   // (NT+1) * log 16
    atomicAdd(out, (Cc + Q + CONST) - realp);
  }
}

extern "C" void kernel_launch(void* const* d_in, const int* in_sizes, int n_in,
                              void* d_out, int out_size, void* d_ws, size_t ws_size,
                              hipStream_t stream) {
  const float* em  = (const float*)d_in[0];
  const int*   lab = (const int*)d_in[1];
  const float* tr  = (const float*)d_in[2];
  (void)hipMemsetAsync(d_out, 0, sizeof(float), stream);
  crf_kernel<<<NB, 64, 0, stream>>>(em, lab, tr, (float*)d_out);
}

// Round 3
// 577.513 us; speedup vs baseline: 1.2867x; 1.2867x over previous
//
#include <hip/hip_runtime.h>
#include <hip/hip_fp16.h>

#define NB 512   // batch
#define NT 512   // time steps
#define NL 126   // labels
#define NS 128   // states (start=126, end=127)
#define SIGMA 0.0625f   // lagged-normalizer target scale (1/16)

typedef _Float16 h2 __attribute__((ext_vector_type(2)));

static __device__ __forceinline__ int pk_from(float a, float b) {
  return __builtin_bit_cast(int, __builtin_amdgcn_cvt_pkrtz(a, b));
}
// guaranteed-packed fp16 ops on int-carried pairs
static __device__ __forceinline__ int pkmul(int a, int b) {
  int d; asm("v_pk_mul_f16 %0, %1, %2" : "=v"(d) : "v"(a), "v"(b)); return d;
}
static __device__ __forceinline__ int pkmax(int a, int b) {
  int d; asm("v_pk_max_f16 %0, %1, %2" : "=v"(d) : "v"(a), "v"(b)); return d;
}
static __device__ __forceinline__ int pkadd(int a, int b) {
  int d; asm("v_pk_add_f16 %0, %1, %2" : "=v"(d) : "v"(a), "v"(b)); return d;
}

// wave64 add-reduce to lane 63, ONE instruction per stage (v_add_f32_dpp).
// Same numeric tree as the validated R0-R2 macro.
#define WAVE_ADD(x) do { \
  asm("v_add_f32_dpp %0, %0, %0 row_shr:1  row_mask:0xf bank_mask:0xf bound_ctrl:0" : "+v"(x)); \
  asm("v_add_f32_dpp %0, %0, %0 row_shr:2  row_mask:0xf bank_mask:0xf bound_ctrl:0" : "+v"(x)); \
  asm("v_add_f32_dpp %0, %0, %0 row_shr:4  row_mask:0xf bank_mask:0xf bound_ctrl:0" : "+v"(x)); \
  asm("v_add_f32_dpp %0, %0, %0 row_shr:8  row_mask:0xf bank_mask:0xf bound_ctrl:0" : "+v"(x)); \
  asm("v_add_f32_dpp %0, %0, %0 row_bcast:15 row_mask:0xa bank_mask:0xf bound_ctrl:0" : "+v"(x)); \
  asm("v_add_f32_dpp %0, %0, %0 row_bcast:31 row_mask:0xc bank_mask:0xf bound_ctrl:0" : "+v"(x)); \
} while (0)

// TWO waves per batch element; lane (wave w, lane l) owns column 64w+l, all
// 128 rows. Per-column max/sum tree is entirely in-lane (tab = 64 packed
// ints/lane -> ~160 VGPR total demand, no spill; amdgpu_waves_per_eu(1,1)
// tells the allocator it may use the full register file — launch config is
// 4 waves/CU = 1 wave/SIMD anyway). u-exchange: each lane ds_write_b16's its
// new u, 2-wave barrier, then 16 same-address ds_read_b128 broadcast the full
// 256B u-vector. Ping-pong buffers + lagged S/Z partials (validated R5 math,
// same tab packing and fp16 tree as the absmax-0.0 rounds).
__global__ __launch_bounds__(128) __attribute__((amdgpu_waves_per_eu(1, 1)))
void crf_kernel(
    const float* __restrict__ emissions,   // [NB, NT, NL]
    const int*   __restrict__ labels,      // [NB, NT]
    const float* __restrict__ trans,       // [NS, NS]
    float*       __restrict__ out)
{
  const int b   = blockIdx.x;
  const int tid = threadIdx.x;            // 0..127
  const int wv  = tid >> 6;               // wave 0..1
  const int ln  = tid & 63;
  const int col = tid;                    // column 0..127 owned by this lane
  const bool has = (col < NL);

  __shared__ __align__(16) _Float16 u_sh[2][NS];  // ping-pong u buffers, 256B each
  __shared__ float sPart[2][2];                   // [slot][wave]
  __shared__ float zPart[2][2];
  __shared__ float fin[2];

  const float* em  = emissions + (size_t)b * NT * NL;
  const int*   lab = labels + (size_t)b * NT;

  // ---- per-column max tau (exact fp32) ----
  float tau = -3.0e38f;
  for (int rr = 0; rr < NS; rr++) tau = fmaxf(tau, trans[rr * NS + col]);

  // ---- tab[k] = rows (2k, 2k+1) of exp(T[.][col]-tau), packed fp16 ----
  int tab[64];
  #pragma unroll
  for (int k = 0; k < 64; k++) {
    float t0 = __expf(trans[(2 * k) * NS + col] - tau);
    float t1 = __expf(trans[(2 * k + 1) * NS + col] - tau);
    tab[k] = pk_from(t0, t1);
  }

  // ---- gold path partial (4 timesteps per thread) ----
  float realp = 0.f;
  #pragma unroll
  for (int q = 0; q < NT / 128; q++) {
    int t  = tid + q * 128;
    int la = lab[t];
    int na = (t + 1 < NT) ? lab[t + 1] : (NL + 1);
    realp += em[t * NL + la] + trans[la * NS + na];
  }
  if (tid == 0) realp += trans[NL * NS + lab[0]];

  // ---- init: v = delta at start state (col 126), buffer 0 ----
  u_sh[0][col] = (_Float16)((col == NL) ? 1.f : 0.f);

  // ---- rolling 2-deep emission prefetch (4B per lane, coalesced) ----
  float emc = has ? em[col] : 0.f;
  float emn = has ? em[NL + col] : 0.f;

  float Cc = 0.f, Q = 0.f;
  __syncthreads();

  #pragma unroll 2
  for (int t = 0; t <= NT; t++) {
    const int sl = t & 1;

    // ---- lagged scalars from step t-1 (slot t&1) ----
    float r;
    if (t > 0) {
      float S = sPart[sl][0] + sPart[sl][1];
      float Z = zPart[sl][0] + zPart[sl][1];
      Cc += __logf(S);
      Q  += __logf(Z);
      r = SIGMA * __builtin_amdgcn_rcpf(Z);
    } else {
      r = SIGMA;                       // Z(init) = 1
    }

    // ---- g = exp(obs + tau) from prefetched emission ----
    float obs;
    if (t < NT) obs = has ? emc : -1000.f;
    else        obs = (col == NL + 1) ? 0.f : -1000.f;
    float g = __expf(obs + tau);

    // issue t+2 emission prefetch early (hides under the tree)
    float ef = (t + 2 < NT && has) ? em[(t + 2) * NL + col] : 0.f;
    emc = emn; emn = ef;

    // ---- broadcast-read the whole u vector (16x same-address b128) ----
    const int4* up = (const int4*)u_sh[sl];
    int4 uu[16];
    #pragma unroll
    for (int j = 0; j < 16; j++) uu[j] = up[j];

    // ---- critical path: 128 rows of this lane's column, 8 acc chains ----
    int ha = 0, hb = 0, hcc = 0, hd = 0;
    int sa = 0, sb = 0, scc = 0, sd = 0;
    #pragma unroll
    for (int j = 0; j < 16; j++) {
      int m;
      m = pkmul(uu[j].x, tab[4*j+0]); ha  = pkmax(ha,  m); sa  = pkadd(sa,  m);
      m = pkmul(uu[j].y, tab[4*j+1]); hb  = pkmax(hb,  m); sb  = pkadd(sb,  m);
      m = pkmul(uu[j].z, tab[4*j+2]); hcc = pkmax(hcc, m); scc = pkadd(scc, m);
      m = pkmul(uu[j].w, tab[4*j+3]); hd  = pkmax(hd,  m); sd  = pkadd(sd,  m);
    }
    int hv = pkmax(pkmax(ha, hb), pkmax(hcc, hd));
    int sv = pkadd(pkadd(sa, sb), pkadd(scc, sd));
    h2 hh = __builtin_bit_cast(h2, hv);
    h2 ss = __builtin_bit_cast(h2, sv);
    float h = fmaxf(fmaxf((float)hh.x, (float)hh.y), 1e-30f);
    float s = (float)ss.x + (float)ss.y;

    float w = h * g;
    float v = w * r;
    u_sh[sl ^ 1][col] = (_Float16)v;   // single b16 write per lane

    // ---- reductions for next step's lagged scalars ----
    float contrib = s * __builtin_amdgcn_rcpf(h);
    float zz = v;
    WAVE_ADD(contrib);
    WAVE_ADD(zz);
    if (ln == 63) {
      sPart[sl ^ 1][wv] = contrib;
      zPart[sl ^ 1][wv] = zz;
    }
    __syncthreads();                   // the ONLY barrier per step (2 waves)
  }

  // ---- final scalars of step NT (slot (NT+1)&1 = 1) ----
  {
    float S = sPart[1][0] + sPart[1][1];
    float Z = zPart[1][0] + zPart[1][1];
    Cc += __logf(S);
    Q  += __logf(Z);
  }

  // total = Cc + Q + (NT+1)*log(1/SIGMA); one atomic per block
  WAVE_ADD(realp);
  if (ln == 63) fin[wv] = realp;
  __syncthreads();
  if (tid == 0) {
    const float CONST = 513.f * 2.772588722f;   // (NT+1) * log 16
    atomicAdd(out, (Cc + Q + CONST) - (fin[0] + fin[1]));
  }
}

extern "C" void kernel_launch(void* const* d_in, const int* in_sizes, int n_in,
                              void* d_out, int out_size, void* d_ws, size_t ws_size,
                              hipStream_t stream) {
  const float* em  = (const float*)d_in[0];
  const int*   lab = (const int*)d_in[1];
  const float* tr  = (const float*)d_in[2];
  (void)hipMemsetAsync(d_out, 0, sizeof(float), stream);
  crf_kernel<<<NB, 128, 0, stream>>>(em, lab, tr, (float*)d_out);
}